// Round 6
// baseline (51.388 us; speedup 1.0000x reference)
//
#include <hip/hip_runtime.h>
#include <math.h>

#define TOPK 8
#define KJ 17
#define BB 512
#define NROWS (BB * KJ)   // 8704
#define DF 3072           // floats per row; 768 float4; 3 float4/thread @ 256 thr

// Single kernel, one block per (b,k) row. Tail fused via DISTRIBUTED counters:
//  - publish loss[row] with agent-scope relaxed store (write-through, no fence)
//  - s_waitcnt vmcnt(0), then relaxed RMW on counter[b] (512 lines, 17 RMWs each)
//  - block seeing old==16 owns sample b: top-8 of its 17 losses -> persample[b],
//    RMW wincount; block seeing old==511 reduces persample[512] -> d_out.
// No spinning, no device fences (R2: fence x8704 = +276us; R3: 1-line RMW
// x8704 = +83us — both avoided).
__global__ __launch_bounds__(256) void ohkm_fused_kernel(
    const float* __restrict__ out,
    const float* __restrict__ tgt,
    const float* __restrict__ w,
    int* __restrict__ counter,      // [BB]
    int* __restrict__ wincount,     // [1]
    float* __restrict__ persample,  // [BB]
    float* __restrict__ loss,       // [NROWS]
    float* __restrict__ result)
{
    const int row = blockIdx.x;
    const int b_s = row / KJ;
    const int tid = threadIdx.x;
    const size_t base = (size_t)row * DF;
    const float4* __restrict__ o4 = (const float4*)(out + base);
    const float4* __restrict__ t4 = (const float4*)(tgt + base);

    float4 a0 = o4[tid];
    float4 a1 = o4[tid + 256];
    float4 a2 = o4[tid + 512];
    float4 b0 = t4[tid];
    float4 b1 = t4[tid + 256];
    float4 b2 = t4[tid + 512];

    float dx = a0.x - b0.x, dy = a0.y - b0.y, dz = a0.z - b0.z, dw = a0.w - b0.w;
    float acc = dx * dx + dy * dy + dz * dz + dw * dw;
    dx = a1.x - b1.x; dy = a1.y - b1.y; dz = a1.z - b1.z; dw = a1.w - b1.w;
    acc += dx * dx + dy * dy + dz * dz + dw * dw;
    dx = a2.x - b2.x; dy = a2.y - b2.y; dz = a2.z - b2.z; dw = a2.w - b2.w;
    acc += dx * dx + dy * dy + dz * dz + dw * dw;

    #pragma unroll
    for (int off = 32; off > 0; off >>= 1)
        acc += __shfl_down(acc, off, 64);

    __shared__ float s[4];
    __shared__ int s_old;
    const int lane = tid & 63;
    const int wid = tid >> 6;
    if (lane == 0) s[wid] = acc;
    __syncthreads();
    if (tid == 0) {
        float tot = (s[0] + s[1] + s[2] + s[3]) * w[row];
        __hip_atomic_store(&loss[row], tot, __ATOMIC_RELAXED,
                           __HIP_MEMORY_SCOPE_AGENT);
        asm volatile("s_waitcnt vmcnt(0)" ::: "memory");
        s_old = __hip_atomic_fetch_add(&counter[b_s], 1, __ATOMIC_RELAXED,
                                       __HIP_MEMORY_SCOPE_AGENT);
    }
    __syncthreads();
    if (s_old != KJ - 1) return;

    // ---- sample-winner phase: this block is last of sample b_s ----
    __shared__ float s_loss[KJ];
    __shared__ int s_fin;
    if (tid < KJ)
        s_loss[tid] = __hip_atomic_load(&loss[b_s * KJ + tid],
                                        __ATOMIC_RELAXED, __HIP_MEMORY_SCOPE_AGENT);
    __syncthreads();
    if (tid == 0) {
        float v[KJ];
        #pragma unroll
        for (int k = 0; k < KJ; ++k) v[k] = s_loss[k];
        float sum8 = 0.0f;
        #pragma unroll
        for (int it = 0; it < TOPK; ++it) {
            float m = v[0];
            int mi = 0;
            #pragma unroll
            for (int k = 1; k < KJ; ++k)
                if (v[k] > m) { m = v[k]; mi = k; }
            sum8 += m;
            #pragma unroll
            for (int k = 0; k < KJ; ++k)
                v[k] = (k == mi) ? -INFINITY : v[k];
        }
        __hip_atomic_store(&persample[b_s], sum8 * (1.0f / (float)TOPK),
                           __ATOMIC_RELAXED, __HIP_MEMORY_SCOPE_AGENT);
        asm volatile("s_waitcnt vmcnt(0)" ::: "memory");
        s_fin = __hip_atomic_fetch_add(wincount, 1, __ATOMIC_RELAXED,
                                       __HIP_MEMORY_SCOPE_AGENT);
    }
    __syncthreads();
    if (s_fin != BB - 1) return;

    // ---- final phase: exactly one block reduces the 512 per-sample means ----
    float per = __hip_atomic_load(&persample[tid],
                                  __ATOMIC_RELAXED, __HIP_MEMORY_SCOPE_AGENT)
              + __hip_atomic_load(&persample[tid + 256],
                                  __ATOMIC_RELAXED, __HIP_MEMORY_SCOPE_AGENT);
    #pragma unroll
    for (int off = 32; off > 0; off >>= 1)
        per += __shfl_down(per, off, 64);

    __shared__ float s2[4];
    if (lane == 0) s2[wid] = per;
    __syncthreads();
    if (tid == 0)
        result[0] = (s2[0] + s2[1] + s2[2] + s2[3]) / (float)BB;
}

extern "C" void kernel_launch(void* const* d_in, const int* in_sizes, int n_in,
                              void* d_out, int out_size, void* d_ws, size_t ws_size,
                              hipStream_t stream) {
    const float* out_p = (const float*)d_in[0];
    const float* tgt_p = (const float*)d_in[1];
    const float* w_p   = (const float*)d_in[2];
    float* res = (float*)d_out;

    // d_ws layout: counter[512] @0 (2048B) | wincount @2048 | pad |
    //              persample[512] @4096 | loss[8704] @8192
    int*   counter   = (int*)d_ws;
    int*   wincount  = (int*)((char*)d_ws + 2048);
    float* persample = (float*)((char*)d_ws + 4096);
    float* loss_ws   = (float*)((char*)d_ws + 8192);

    hipMemsetAsync(d_ws, 0, 4096, stream);  // counters + wincount
    ohkm_fused_kernel<<<NROWS, 256, 0, stream>>>(out_p, tgt_p, w_p,
                                                 counter, wincount,
                                                 persample, loss_ws, res);
}

// Round 7
// 39.872 us; speedup vs baseline: 1.2888x; 1.2888x over previous
//
#include <hip/hip_runtime.h>
#include <math.h>

#define TOPK 8
#define KJ 17
#define BB 512
#define NROWS (BB * KJ)   // 8704
#define DF 3072           // floats per row; 768 float4; 3 float4/thread @ 256 thr

// Kernel 1: one block per (b,k) row. Writes loss TRANSPOSED as loss[k*BB+b]
// so kernel2's per-thread reads are coalesced (R6 post-mortem: kernel2 was
// latency-bound on 68B-strided reads).
__global__ __launch_bounds__(256) void row_loss_kernel(
    const float* __restrict__ out,
    const float* __restrict__ tgt,
    const float* __restrict__ w,
    float* __restrict__ loss)   // [KJ][BB] transposed
{
    const int row = blockIdx.x;
    const int tid = threadIdx.x;
    const size_t base = (size_t)row * DF;
    const float4* __restrict__ o4 = (const float4*)(out + base);
    const float4* __restrict__ t4 = (const float4*)(tgt + base);

    float4 a0 = o4[tid];
    float4 a1 = o4[tid + 256];
    float4 a2 = o4[tid + 512];
    float4 b0 = t4[tid];
    float4 b1 = t4[tid + 256];
    float4 b2 = t4[tid + 512];

    float dx = a0.x - b0.x, dy = a0.y - b0.y, dz = a0.z - b0.z, dw = a0.w - b0.w;
    float acc = dx * dx + dy * dy + dz * dz + dw * dw;
    dx = a1.x - b1.x; dy = a1.y - b1.y; dz = a1.z - b1.z; dw = a1.w - b1.w;
    acc += dx * dx + dy * dy + dz * dz + dw * dw;
    dx = a2.x - b2.x; dy = a2.y - b2.y; dz = a2.z - b2.z; dw = a2.w - b2.w;
    acc += dx * dx + dy * dy + dz * dz + dw * dw;

    #pragma unroll
    for (int off = 32; off > 0; off >>= 1)
        acc += __shfl_down(acc, off, 64);

    __shared__ float s[4];
    const int lane = tid & 63;
    const int wid = tid >> 6;
    if (lane == 0) s[wid] = acc;
    __syncthreads();
    if (tid == 0) {
        const int b_s = row / KJ;       // scalar magic-mul, cheap
        const int k_s = row - b_s * KJ;
        loss[k_s * BB + b_s] = (s[0] + s[1] + s[2] + s[3]) * w[row];
    }
}

// Kernel 2: single block, one thread per batch element b. Coalesced loads
// from the transposed loss layout.
__global__ __launch_bounds__(512) void topk_mean_kernel(
    const float* __restrict__ loss,   // [KJ][BB]
    float* __restrict__ outp)
{
    const int b = threadIdx.x;
    float per;

    {
        float v[KJ];
        #pragma unroll
        for (int k = 0; k < KJ; ++k)
            v[k] = loss[k * BB + b];

        float sum8 = 0.0f;
        #pragma unroll
        for (int it = 0; it < TOPK; ++it) {
            float m = v[0];
            int mi = 0;
            #pragma unroll
            for (int k = 1; k < KJ; ++k)
                if (v[k] > m) { m = v[k]; mi = k; }
            sum8 += m;
            #pragma unroll
            for (int k = 0; k < KJ; ++k)
                v[k] = (k == mi) ? -INFINITY : v[k];
        }
        per = sum8 * (1.0f / (float)TOPK);
    }

    #pragma unroll
    for (int off = 32; off > 0; off >>= 1)
        per += __shfl_down(per, off, 64);

    __shared__ float s[8];
    const int lane = threadIdx.x & 63;
    const int wid = threadIdx.x >> 6;
    if (lane == 0) s[wid] = per;
    __syncthreads();
    if (threadIdx.x == 0) {
        float tot = 0.0f;
        #pragma unroll
        for (int i = 0; i < 8; ++i) tot += s[i];
        outp[0] = tot / (float)BB;
    }
}

extern "C" void kernel_launch(void* const* d_in, const int* in_sizes, int n_in,
                              void* d_out, int out_size, void* d_ws, size_t ws_size,
                              hipStream_t stream) {
    const float* out_p = (const float*)d_in[0];
    const float* tgt_p = (const float*)d_in[1];
    const float* w_p   = (const float*)d_in[2];
    float* res = (float*)d_out;

    float* loss_ws = (float*)d_ws;  // NROWS floats, [KJ][BB] layout

    row_loss_kernel<<<NROWS, 256, 0, stream>>>(out_p, tgt_p, w_p, loss_ws);
    topk_mean_kernel<<<1, 512, 0, stream>>>(loss_ws, res);
}